// Round 12
// baseline (193.487 us; speedup 1.0000x reference)
//
#include <hip/hip_runtime.h>
#include <stdint.h>

#define B_   8
#define L_   1024
#define DM   512
#define DI   1024
#define DS   16
#define DTR  32
#define M_   (B_*L_)   // 8192 tokens

typedef short v8s __attribute__((ext_vector_type(8)));
typedef short v4s __attribute__((ext_vector_type(4)));
typedef float v4f __attribute__((ext_vector_type(4)));

static __device__ __forceinline__ short f2bf(float f) {
  union { float f; uint32_t u; } v; v.f = f;
  uint32_t r = v.u + 0x7FFFu + ((v.u >> 16) & 1u);
  return (short)(r >> 16);
}
static __device__ __forceinline__ float bf2f(short s) {
  union { uint32_t u; float f; } v; v.u = ((uint32_t)(uint16_t)s) << 16; return v.f;
}
static __device__ __forceinline__ float silu_fast(float a) {
  return a * __builtin_amdgcn_rcpf(1.f + __expf(-a));
}
static __device__ __forceinline__ float wsum(float v) {
#pragma unroll
  for (int o = 32; o > 0; o >>= 1) v += __shfl_xor(v, o, 64);
  return v;
}
static __device__ __forceinline__ void gl_lds16(const short* g, short* l) {
  __builtin_amdgcn_global_load_lds(
      (const __attribute__((address_space(1))) void*)g,
      (__attribute__((address_space(3))) void*)l, 16, 0, 0);
}

// ------- prep: casts + Aneg + zlast (independent sections merged) ------------
__global__ __launch_bounds__(256) void k_prep(const float* __restrict__ x,
                                              const float* __restrict__ w_in,
                                              const float* __restrict__ w_x,
                                              const float* __restrict__ w_dt,
                                              const float* __restrict__ a_log,
                                              short* xb, short* wib, short* wxb, short* wdtb,
                                              float* Aneg, float* zlast) {
  if (blockIdx.x >= 4704) {
    // zlast[b, j] = x[b, L-1, :] . W_in[DI + j, :]
    int w = (int)(blockIdx.x - 4704) * 4 + (threadIdx.x >> 6);  // 0..8191
    int l = threadIdx.x & 63;
    int b = w >> 10, j = w & 1023;
    const v4f* xr = (const v4f*)(x + ((size_t)(b * L_ + L_ - 1)) * DM);
    const v4f* wr = (const v4f*)(w_in + (size_t)(DI + j) * DM);
    float s = 0.f;
#pragma unroll
    for (int i = 0; i < 2; ++i) {
      v4f a = xr[l + 64 * i], c = wr[l + 64 * i];
      s += a[0]*c[0] + a[1]*c[1] + a[2]*c[2] + a[3]*c[3];
    }
    s = wsum(s);
    if (l == 0) zlast[b * DI + j] = s;
    return;
  }
  int idx = (blockIdx.x * 256 + threadIdx.x) * 4;
  const int n0 = M_ * DM, n1 = DI * DM, n2 = 48 * DI, n3 = DI * DTR, n4 = DI * DS;
  const float* src; short* dst;
  if (idx < n0)              { src = x + idx;    dst = xb + idx; }
  else if ((idx -= n0) < n1) { src = w_in + idx; dst = wib + idx; }
  else if ((idx -= n1) < n2) { src = w_x + idx;  dst = wxb + idx; }
  else if ((idx -= n2) < n3) { src = w_dt + idx; dst = wdtb + idx; }
  else if ((idx -= n3) < n4) {
    v4f v = *(const v4f*)(a_log + idx);
    v4f o;
#pragma unroll
    for (int i = 0; i < 4; ++i) o[i] = -__expf(v[i]);
    *(v4f*)(Aneg + idx) = o;
    return;
  }
  else return;
  v4f v = *(const v4f*)src;
  v4s o;
#pragma unroll
  for (int i = 0; i < 4; ++i) o[i] = f2bf(v[i]);
  *(v4s*)dst = o;
}

// ------- fused: xi GEMM (128x128 tile, BK=64) + causal conv + silu -> xcb ----
// Tile rows = 128 consecutive tokens of one batch (1024/128=8 tiles/batch, no
// straddle). Conv halo (3 tokens) recomputed via direct bf16 dots (wib is L2-hot).
__global__ __launch_bounds__(256) void k_gemm_xi_conv(const short* __restrict__ xb,
                                                      const short* __restrict__ wib,
                                                      const float* __restrict__ conv_w,
                                                      const float* __restrict__ conv_b,
                                                      short* __restrict__ xcb,
                                                      float* __restrict__ xclast) {
  __shared__ short sh[128 * 136];          // 34 KB; lA/lB alias the front
  __shared__ short hs[3 * 128];            // halo xi (3 tokens x 128 cols)
  short* lA = sh;                          // 128*64
  short* lB = sh + 128 * 64;               // 128*64
  int mb = blockIdx.x >> 3, nb = blockIdx.x & 7;
  int tid = threadIdx.x;
  int w = tid >> 6, l = tid & 63, lm = l & 15, q = l >> 4;
  int wm = (w >> 1) * 64, wn = (w & 1) * 64;

  v4f acc[4][4];
#pragma unroll
  for (int i = 0; i < 4; ++i)
#pragma unroll
    for (int j = 0; j < 4; ++j) acc[i][j] = (v4f){0,0,0,0};

  int srow_in_chunk = l >> 3;
  int sslot = l & 7;
  const short* Abase = xb  + (size_t)(mb * 128) * DM;
  const short* Bbase = wib + (size_t)(nb * 128) * DM;

  for (int k0 = 0; k0 < DM; k0 += 64) {
    if (k0) __syncthreads();
#pragma unroll
    for (int i = 0; i < 4; ++i) {
      int chunk = w * 4 + i;
      int row = chunk * 8 + srow_in_chunk;
      int c = sslot ^ (row & 7);
      gl_lds16(Abase + (size_t)row * DM + k0 + c * 8, lA + chunk * 512);
      gl_lds16(Bbase + (size_t)row * DM + k0 + c * 8, lB + chunk * 512);
    }
    __syncthreads();
#pragma unroll
    for (int kt = 0; kt < 2; ++kt) {
      v8s af[4], bf[4];
      int p = (kt * 4 + q) ^ (lm & 7);
#pragma unroll
      for (int t = 0; t < 4; ++t) {
        af[t] = *(const v8s*)(lA + (wm + t * 16 + lm) * 64 + p * 8);
        bf[t] = *(const v8s*)(lB + (wn + t * 16 + lm) * 64 + p * 8);
      }
#pragma unroll
      for (int i = 0; i < 4; ++i)
#pragma unroll
        for (int j = 0; j < 4; ++j)
          acc[i][j] = __builtin_amdgcn_mfma_f32_16x16x32_bf16(af[i], bf[j], acc[i][j], 0, 0, 0);
    }
  }
  // stage C (col=lm, row=q*4+r) -> LDS (stride 136)
  __syncthreads();
#pragma unroll
  for (int i = 0; i < 4; ++i)
#pragma unroll
    for (int r = 0; r < 4; ++r) {
      int row = wm + i * 16 + q * 4 + r;
#pragma unroll
      for (int j = 0; j < 4; ++j)
        sh[row * 136 + wn + j * 16 + lm] = f2bf(acc[i][j][r]);
    }
  // halo xi for tokens t0-3..t0-1 (zeros at batch start)
  {
    int t0 = (mb & 7) * 128;
    int c = tid & 127;
    if (t0 == 0) {
      if (tid < 128) { hs[c] = 0; hs[128 + c] = 0; }
      else           { hs[256 + c] = 0; }
    } else {
      const short* wrow = wib + (size_t)(nb * 128 + c) * DM;
      if (tid < 128) {
        const short* a0p = xb + (size_t)(mb * 128 - 3) * DM;
        const short* a1p = xb + (size_t)(mb * 128 - 2) * DM;
        float s0 = 0.f, s1 = 0.f;
        for (int k = 0; k < DM; k += 8) {
          v8s wv  = *(const v8s*)(wrow + k);
          v8s av0 = *(const v8s*)(a0p + k);
          v8s av1 = *(const v8s*)(a1p + k);
#pragma unroll
          for (int i = 0; i < 8; ++i) {
            float wf = bf2f(wv[i]);
            s0 += bf2f(av0[i]) * wf;
            s1 += bf2f(av1[i]) * wf;
          }
        }
        hs[c] = f2bf(s0); hs[128 + c] = f2bf(s1);
      } else {
        const short* a2p = xb + (size_t)(mb * 128 - 1) * DM;
        float s2 = 0.f;
        for (int k = 0; k < DM; k += 8) {
          v8s wv  = *(const v8s*)(wrow + k);
          v8s av2 = *(const v8s*)(a2p + k);
#pragma unroll
          for (int i = 0; i < 8; ++i) s2 += bf2f(av2[i]) * bf2f(wv[i]);
        }
        hs[256 + c] = f2bf(s2);
      }
    }
  }
  __syncthreads();
  // conv + silu down the tile; thread = (col, half): 64 tokens each
  {
    int c = tid & 127, th = tid >> 7;
    int gcol = nb * 128 + c;
    v4f cw = *(const v4f*)(conv_w + gcol * 4);
    float cb = conv_b[gcol];
    float w0, w1, w2;
    if (th == 0) {
      w0 = bf2f(hs[c]); w1 = bf2f(hs[128 + c]); w2 = bf2f(hs[256 + c]);
    } else {
      w0 = bf2f(sh[61 * 136 + c]); w1 = bf2f(sh[62 * 136 + c]); w2 = bf2f(sh[63 * 136 + c]);
    }
    size_t outbase = (size_t)(mb * 128 + th * 64) * DI + gcol;
    bool lastblk = ((mb & 7) == 7) && (th == 1);
    int b = mb >> 3;
    for (int r = 0; r < 64; ++r) {
      float xv = bf2f(sh[(th * 64 + r) * 136 + c]);
      float a = cb + cw[0] * w0 + cw[1] * w1 + cw[2] * w2 + cw[3] * xv;
      float s = silu_fast(a);
      xcb[outbase + (size_t)r * DI] = f2bf(s);
      if (lastblk && r == 63) xclast[b * DI + gcol] = s;
      w0 = w1; w1 = w2; w2 = xv;
    }
  }
}

// ------- fused: dbc split-K + Bmat + dt (LDS-staged coalesced store) + csum2 -
__global__ __launch_bounds__(256) void k_dbcdt(const short* __restrict__ xcb,
                                               const short* __restrict__ wxb,
                                               const short* __restrict__ wdtb,
                                               const float* __restrict__ b_dt,
                                               float* __restrict__ Bmat,
                                               _Float16* __restrict__ dtO,
                                               float* __restrict__ csum2) {
  __shared__ union {
    float red[4 * 16 * 49];            // phase 1: split-K reduce (12.5 KB)
    _Float16 dtile[16 * 1024];         // phase 2: dt staging (32 KB)
  } u;
  __shared__ short ta[16 * 32];        // dbc[:, :32] bf16, A-frag source
  int m = blockIdx.x;                  // mtile 0..511 (16 tokens)
  int tid = threadIdx.x, w = tid >> 6, l = tid & 63, lm = l & 15, q = l >> 4;
  v4f a0 = {0,0,0,0}, a1 = {0,0,0,0}, a2 = {0,0,0,0};
  const short* ap = xcb + (size_t)(m * 16 + lm) * DI + w * 256 + q * 8;
  const short* b0 = wxb + (size_t)lm * DI        + w * 256 + q * 8;
  const short* b1 = wxb + (size_t)(16 + lm) * DI + w * 256 + q * 8;
  const short* b2 = wxb + (size_t)(32 + lm) * DI + w * 256 + q * 8;
#pragma unroll
  for (int kk = 0; kk < 8; ++kk) {
    v8s a = *(const v8s*)(ap + kk * 32);
    a0 = __builtin_amdgcn_mfma_f32_16x16x32_bf16(a, *(const v8s*)(b0 + kk * 32), a0, 0, 0, 0);
    a1 = __builtin_amdgcn_mfma_f32_16x16x32_bf16(a, *(const v8s*)(b1 + kk * 32), a1, 0, 0, 0);
    a2 = __builtin_amdgcn_mfma_f32_16x16x32_bf16(a, *(const v8s*)(b2 + kk * 32), a2, 0, 0, 0);
  }
#pragma unroll
  for (int r = 0; r < 4; ++r) {
    int row = q * 4 + r;
    u.red[w * 784 + row * 49 + lm]      = a0[r];
    u.red[w * 784 + row * 49 + 16 + lm] = a1[r];
    u.red[w * 784 + row * 49 + 32 + lm] = a2[r];
  }
  __syncthreads();
  {
    int row = tid >> 4, c0 = tid & 15;
    int base = row * 49 + c0;
    float s0 = u.red[base] + u.red[784 + base] + u.red[1568 + base] + u.red[2352 + base];
    float s1 = u.red[base + 16] + u.red[784 + base + 16] + u.red[1568 + base + 16] + u.red[2352 + base + 16];
    float s2 = u.red[base + 32] + u.red[784 + base + 32] + u.red[1568 + base + 32] + u.red[2352 + base + 32];
    ta[row * 32 + c0]      = f2bf(s0);
    ta[row * 32 + 16 + c0] = f2bf(s1);
    Bmat[(size_t)(m * 16 + row) * DS + c0] = s2;
  }
  __syncthreads();   // red reads done; u.dtile may now be written
  // phase 2: dt = softplus(dbc32 @ W_dt.T + b_dt) -> LDS tile, then coalesced
  v8s ad = *(const v8s*)(ta + lm * 32 + q * 8);
#pragma unroll 4
  for (int nn = 0; nn < 16; ++nn) {
    int nt = w * 16 + nn;
    v8s bb = *(const v8s*)(wdtb + (size_t)(nt * 16 + lm) * DTR + q * 8);
    v4f zz = {0,0,0,0};
    v4f dd = __builtin_amdgcn_mfma_f32_16x16x32_bf16(ad, bb, zz, 0, 0, 0);
    int col = nt * 16 + lm;
    float bd = b_dt[col];
    float s = 0.f;
#pragma unroll
    for (int r = 0; r < 4; ++r) {
      float v = dd[r] + bd;
      float sp = (v > 15.f) ? v : __logf(1.f + __expf(v));
      u.dtile[(q * 4 + r) * 1024 + col] = (_Float16)sp;
      s += sp;
    }
    s += __shfl_xor(s, 16, 64);
    s += __shfl_xor(s, 32, 64);
    if (q == 0) csum2[(size_t)m * DI + col] = s;
  }
  __syncthreads();
  // coalesced dt write: 16 rows x 2 KB, 8 B per thread per row
#pragma unroll
  for (int row = 0; row < 16; ++row) {
    v4s v = *(const v4s*)(u.dtile + row * 1024 + tid * 4);
    *(v4s*)(dtO + (size_t)(m * 16 + row) * DI + tid * 4) = v;
  }
}

// ------- suffix sums + C_last (merged small kernels, r8-proven) --------------
__global__ __launch_bounds__(256) void k_sufc(const float* __restrict__ csum2,
                                              const float* __restrict__ xclast,
                                              const float* __restrict__ w_x,
                                              float* __restrict__ SS,
                                              float* __restrict__ clast) {
  if (blockIdx.x < 32) {
    int b = blockIdx.x >> 2, dseg = blockIdx.x & 3;
    int d = dseg * 256 + threadIdx.x;
    float run = 0.f;
    for (int ch = 31; ch >= 0; --ch) {
      SS[(size_t)(b * 32 + ch) * DI + d] = run;
      run += csum2[(size_t)(b * 64 + 2 * ch + 1) * DI + d]
           + csum2[(size_t)(b * 64 + 2 * ch) * DI + d];
    }
  } else {
    int w2 = (int)(blockIdx.x - 32) * 4 + (threadIdx.x >> 6);  // 0..127
    int l = threadIdx.x & 63;
    int b = w2 >> 4, ss = w2 & 15;
    const v4f* xr = (const v4f*)(xclast + (size_t)b * DI);
    const v4f* wr = (const v4f*)(w_x + (size_t)(48 + ss) * DI);
    float s = 0.f;
#pragma unroll
    for (int i = 0; i < 4; ++i) {
      v4f a = xr[l + 64 * i], c = wr[l + 64 * i];
      s += a[0]*c[0] + a[1]*c[1] + a[2]*c[2] + a[3]*c[3];
    }
    s = wsum(s);
    if (l == 0) clast[b * 16 + ss] = s;
  }
}

// ---------------- scan collapsed to suffix-weighted reduction ----------------
__global__ __launch_bounds__(256) void k_scan(const _Float16* __restrict__ dt,
                                              const short* __restrict__ xcb,
                                              const float* __restrict__ Bmat,
                                              const float* __restrict__ SS,
                                              const float* __restrict__ Aneg,
                                              const float* __restrict__ clast,
                                              float* __restrict__ ypart) {
  __shared__ float lB[32 * 16];
  int bid = blockIdx.x;           // 8 b * 32 ch * 4 dg = 1024
  int b = bid >> 7, ch = (bid >> 2) & 31, dg = bid & 3;
  int tid = threadIdx.x;
  for (int i = tid; i < 32 * 16; i += 256)
    lB[i] = Bmat[(size_t)(b * L_ + ch * 32) * DS + i];
  __syncthreads();
  int d = dg * 256 + tid;
  float S = SS[(size_t)(b * 32 + ch) * DI + d];
  float As2[16];
#pragma unroll
  for (int s = 0; s < 16; ++s) As2[s] = Aneg[d * 16 + s] * 1.44269504f;
  float h[16];
#pragma unroll
  for (int s = 0; s < 16; ++s) h[s] = 0.f;
  const _Float16* dtp = dt + ((size_t)(b * L_ + ch * 32)) * DI + d;
  const short* xcp = xcb + ((size_t)(b * L_ + ch * 32)) * DI + d;
  for (int tl = 31; tl >= 0; --tl) {
    float dtv = (float)dtp[(size_t)tl * DI];
    float u   = bf2f(xcp[(size_t)tl * DI]);
    float c = dtv * u;
#pragma unroll
    for (int s = 0; s < 16; ++s)
      h[s] += __builtin_amdgcn_exp2f(As2[s] * S) * (c * lB[tl * 16 + s]);
    S += dtv;
  }
  float yp = 0.f;
#pragma unroll
  for (int s = 0; s < 16; ++s) yp += h[s] * clast[b * 16 + s];
  ypart[(size_t)(b * 32 + ch) * DI + d] = yp;
}

// ---------------- ylast = (sum ypart + D*xc_last) * silu(z_last) -------------
__global__ __launch_bounds__(256) void k_ylast(const float* __restrict__ ypart,
                                               const float* __restrict__ xclast,
                                               const float* __restrict__ Dp,
                                               const float* __restrict__ zlast,
                                               float* __restrict__ ylast) {
  int idx = blockIdx.x * 256 + threadIdx.x;  // 8192
  int b = idx >> 10, d = idx & 1023;
  float acc = 0.f;
#pragma unroll 8
  for (int ch = 0; ch < 32; ++ch) acc += ypart[(size_t)(b * 32 + ch) * DI + d];
  float y = acc + Dp[d] * xclast[idx];
  ylast[idx] = y * silu_fast(zlast[idx]);
}

// ---------------- out_last = y_last @ W_out.T (one output per wave) ----------
__global__ __launch_bounds__(256) void k_out(const float* __restrict__ ylast,
                                             const float* __restrict__ w_out,
                                             float* __restrict__ olast) {
  int w = blockIdx.x * 4 + (threadIdx.x >> 6);  // 4096
  int l = threadIdx.x & 63;
  int b = w >> 9, i = w & 511;
  const v4f* yr = (const v4f*)(ylast + (size_t)b * DI);
  const v4f* wr = (const v4f*)(w_out + (size_t)i * DI);
  float s = 0.f;
#pragma unroll
  for (int k = 0; k < 4; ++k) {
    v4f a = yr[l + 64 * k], c = wr[l + 64 * k];
    s += a[0]*c[0] + a[1]*c[1] + a[2]*c[2] + a[3]*c[3];
  }
  s = wsum(s);
  if (l == 0) olast[b * DM + i] = s;
}

// ---------------- layer norm over last token ---------------------------------
__global__ __launch_bounds__(256) void k_ln(const float* __restrict__ olast,
                                            const float* __restrict__ g,
                                            const float* __restrict__ be,
                                            float* __restrict__ lastn) {
  __shared__ float s1[256], s2[256];
  int b = blockIdx.x, tid = threadIdx.x;
  float v0 = olast[b * DM + tid], v1 = olast[b * DM + 256 + tid];
  s1[tid] = v0 + v1; s2[tid] = v0 * v0 + v1 * v1;
  __syncthreads();
  for (int o = 128; o > 0; o >>= 1) {
    if (tid < o) { s1[tid] += s1[tid + o]; s2[tid] += s2[tid + o]; }
    __syncthreads();
  }
  float mu = s1[0] / (float)DM;
  float var = s2[0] / (float)DM - mu * mu;
  float inv = 1.f / sqrtf(var + 1e-5f);
  lastn[b * DM + tid]       = (v0 - mu) * inv * g[tid]       + be[tid];
  lastn[b * DM + 256 + tid] = (v1 - mu) * inv * g[tid + 256] + be[tid + 256];
}

// ---------------- head GEMM (one output per wave) ----------------------------
__global__ __launch_bounds__(256) void k_head(const float* __restrict__ lastn,
                                              const float* __restrict__ hw,
                                              const float* __restrict__ hb,
                                              float* __restrict__ out) {
  int w = blockIdx.x * 4 + (threadIdx.x >> 6);  // 4096
  int l = threadIdx.x & 63;
  int b = w >> 9, o = w & 511;
  const v4f* xr = (const v4f*)(lastn + (size_t)b * DM);
  const v4f* wr = (const v4f*)(hw + (size_t)o * DM);
  float s = 0.f;
#pragma unroll
  for (int k = 0; k < 2; ++k) {
    v4f a = xr[l + 64 * k], c = wr[l + 64 * k];
    s += a[0]*c[0] + a[1]*c[1] + a[2]*c[2] + a[3]*c[3];
  }
  s = wsum(s);
  if (l == 0) out[b * DM + o] = s + hb[o];
}

extern "C" void kernel_launch(void* const* d_in, const int* in_sizes, int n_in,
                              void* d_out, int out_size, void* d_ws, size_t ws_size,
                              hipStream_t stream) {
  const float* x      = (const float*)d_in[0];
  const float* w_in   = (const float*)d_in[1];
  const float* conv_w = (const float*)d_in[2];
  const float* conv_b = (const float*)d_in[3];
  const float* w_x    = (const float*)d_in[4];
  const float* w_dt   = (const float*)d_in[5];
  const float* b_dt   = (const float*)d_in[6];
  const float* a_log  = (const float*)d_in[7];
  const float* Dp     = (const float*)d_in[8];
  const float* w_out  = (const float*)d_in[9];
  const float* ln_g   = (const float*)d_in[10];
  const float* ln_b   = (const float*)d_in[11];
  const float* head_W = (const float*)d_in[12];
  const float* head_b = (const float*)d_in[13];
  float* out = (float*)d_out;

  char* ws = (char*)d_ws;
  size_t off = 0;
  auto alloc = [&](size_t bytes) { void* p = ws + off; off += (bytes + 255) & ~(size_t)255; return p; };
  short* xb     = (short*)alloc((size_t)M_*DM*2);
  short* wib    = (short*)alloc((size_t)DI*DM*2);
  short* wxb    = (short*)alloc((size_t)48*DI*2);
  short* wdtb   = (short*)alloc((size_t)DI*DTR*2);
  float* Aneg   = (float*)alloc((size_t)DI*DS*4);
  short* xcb    = (short*)alloc((size_t)M_*DI*2);
  _Float16* dt  = (_Float16*)alloc((size_t)M_*DI*2);
  float* Bmat   = (float*)alloc((size_t)M_*DS*4);
  float* csum2  = (float*)alloc((size_t)512*DI*4);
  float* SS     = (float*)alloc((size_t)B_*32*DI*4);
  float* ypart  = (float*)alloc((size_t)B_*32*DI*4);
  float* zlast  = (float*)alloc((size_t)B_*DI*4);
  float* clast  = (float*)alloc((size_t)B_*DS*4);
  float* xclast = (float*)alloc((size_t)B_*DI*4);
  float* ylast  = (float*)alloc((size_t)B_*DI*4);
  float* olast  = (float*)alloc((size_t)B_*DM*4);
  float* lastn  = (float*)alloc((size_t)B_*DM*4);

  k_prep<<<6752, 256, 0, stream>>>(x, w_in, w_x, w_dt, a_log, xb, wib, wxb, wdtb, Aneg, zlast);
  k_gemm_xi_conv<<<512, 256, 0, stream>>>(xb, wib, conv_w, conv_b, xcb, xclast);
  k_dbcdt<<<512, 256, 0, stream>>>(xcb, wxb, wdtb, b_dt, Bmat, dt, csum2);
  k_sufc<<<64, 256, 0, stream>>>(csum2, xclast, w_x, SS, clast);
  k_scan<<<1024, 256, 0, stream>>>(dt, xcb, Bmat, SS, Aneg, clast, ypart);
  k_ylast<<<32, 256, 0, stream>>>(ypart, xclast, Dp, zlast, ylast);
  k_out<<<1024, 256, 0, stream>>>(ylast, w_out, olast);
  k_ln<<<8, 256, 0, stream>>>(olast, ln_g, ln_b, lastn);
  k_head<<<1024, 256, 0, stream>>>(lastn, head_W, head_b, out);
}

// Round 13
// 178.605 us; speedup vs baseline: 1.0833x; 1.0833x over previous
//
#include <hip/hip_runtime.h>
#include <stdint.h>

#define B_   8
#define L_   1024
#define DM   512
#define DI   1024
#define DS   16
#define DTR  32
#define M_   (B_*L_)   // 8192 tokens

typedef short v8s __attribute__((ext_vector_type(8)));
typedef short v4s __attribute__((ext_vector_type(4)));
typedef float v4f __attribute__((ext_vector_type(4)));

static __device__ __forceinline__ short f2bf(float f) {
  union { float f; uint32_t u; } v; v.f = f;
  uint32_t r = v.u + 0x7FFFu + ((v.u >> 16) & 1u);
  return (short)(r >> 16);
}
static __device__ __forceinline__ float bf2f(short s) {
  union { uint32_t u; float f; } v; v.u = ((uint32_t)(uint16_t)s) << 16; return v.f;
}
static __device__ __forceinline__ float silu_fast(float a) {
  return a * __builtin_amdgcn_rcpf(1.f + __expf(-a));
}
static __device__ __forceinline__ float wsum(float v) {
#pragma unroll
  for (int o = 32; o > 0; o >>= 1) v += __shfl_xor(v, o, 64);
  return v;
}
static __device__ __forceinline__ void gl_lds16(const short* g, short* l) {
  __builtin_amdgcn_global_load_lds(
      (const __attribute__((address_space(1))) void*)g,
      (__attribute__((address_space(3))) void*)l, 16, 0, 0);
}

// ------- prep: casts + Aneg + zlast (independent sections merged) ------------
__global__ __launch_bounds__(256) void k_prep(const float* __restrict__ x,
                                              const float* __restrict__ w_in,
                                              const float* __restrict__ w_x,
                                              const float* __restrict__ w_dt,
                                              const float* __restrict__ a_log,
                                              short* xb, short* wib, short* wxb, short* wdtb,
                                              float* Aneg, float* zlast) {
  if (blockIdx.x >= 4704) {
    // zlast[b, j] = x[b, L-1, :] . W_in[DI + j, :]
    int w = (int)(blockIdx.x - 4704) * 4 + (threadIdx.x >> 6);  // 0..8191
    int l = threadIdx.x & 63;
    int b = w >> 10, j = w & 1023;
    const v4f* xr = (const v4f*)(x + ((size_t)(b * L_ + L_ - 1)) * DM);
    const v4f* wr = (const v4f*)(w_in + (size_t)(DI + j) * DM);
    float s = 0.f;
#pragma unroll
    for (int i = 0; i < 2; ++i) {
      v4f a = xr[l + 64 * i], c = wr[l + 64 * i];
      s += a[0]*c[0] + a[1]*c[1] + a[2]*c[2] + a[3]*c[3];
    }
    s = wsum(s);
    if (l == 0) zlast[b * DI + j] = s;
    return;
  }
  int idx = (blockIdx.x * 256 + threadIdx.x) * 4;
  const int n0 = M_ * DM, n1 = DI * DM, n2 = 48 * DI, n3 = DI * DTR, n4 = DI * DS;
  const float* src; short* dst;
  if (idx < n0)              { src = x + idx;    dst = xb + idx; }
  else if ((idx -= n0) < n1) { src = w_in + idx; dst = wib + idx; }
  else if ((idx -= n1) < n2) { src = w_x + idx;  dst = wxb + idx; }
  else if ((idx -= n2) < n3) { src = w_dt + idx; dst = wdtb + idx; }
  else if ((idx -= n3) < n4) {
    v4f v = *(const v4f*)(a_log + idx);
    v4f o;
#pragma unroll
    for (int i = 0; i < 4; ++i) o[i] = -__expf(v[i]);
    *(v4f*)(Aneg + idx) = o;
    return;
  }
  else return;
  v4f v = *(const v4f*)src;
  v4s o;
#pragma unroll
  for (int i = 0; i < 4; ++i) o[i] = f2bf(v[i]);
  *(v4s*)dst = o;
}

// ---------------- xi = x @ W_in[:1024].T : LDS-tiled 128x128, BK=64 ----------
// Staging XOR-swizzled; epilogue staged through LDS for coalesced 16B stores.
__global__ __launch_bounds__(256) void k_gemm_xi(const short* __restrict__ xb,
                                                 const short* __restrict__ wib,
                                                 short* __restrict__ xib) {
  __shared__ short sh[128 * 136];          // 34.8 KB; lA/lB alias the front
  short* lA = sh;                          // 128*64
  short* lB = sh + 128 * 64;               // 128*64
  int mb = blockIdx.x >> 3, nb = blockIdx.x & 7;
  int tid = threadIdx.x;
  int w = tid >> 6, l = tid & 63, lm = l & 15, q = l >> 4;
  int wm = (w >> 1) * 64, wn = (w & 1) * 64;

  v4f acc[4][4];
#pragma unroll
  for (int i = 0; i < 4; ++i)
#pragma unroll
    for (int j = 0; j < 4; ++j) acc[i][j] = (v4f){0,0,0,0};

  int srow_in_chunk = l >> 3;
  int sslot = l & 7;
  const short* Abase = xb  + (size_t)(mb * 128) * DM;
  const short* Bbase = wib + (size_t)(nb * 128) * DM;

  for (int k0 = 0; k0 < DM; k0 += 64) {
    if (k0) __syncthreads();
#pragma unroll
    for (int i = 0; i < 4; ++i) {
      int chunk = w * 4 + i;
      int row = chunk * 8 + srow_in_chunk;
      int c = sslot ^ (row & 7);
      gl_lds16(Abase + (size_t)row * DM + k0 + c * 8, lA + chunk * 512);
      gl_lds16(Bbase + (size_t)row * DM + k0 + c * 8, lB + chunk * 512);
    }
    __syncthreads();
#pragma unroll
    for (int kt = 0; kt < 2; ++kt) {
      v8s af[4], bf[4];
      int p = (kt * 4 + q) ^ (lm & 7);
#pragma unroll
      for (int t = 0; t < 4; ++t) {
        af[t] = *(const v8s*)(lA + (wm + t * 16 + lm) * 64 + p * 8);
        bf[t] = *(const v8s*)(lB + (wn + t * 16 + lm) * 64 + p * 8);
      }
#pragma unroll
      for (int i = 0; i < 4; ++i)
#pragma unroll
        for (int j = 0; j < 4; ++j)
          acc[i][j] = __builtin_amdgcn_mfma_f32_16x16x32_bf16(af[i], bf[j], acc[i][j], 0, 0, 0);
    }
  }
  // epilogue: C (col=lm, row=q*4+r) -> LDS (stride 136) -> coalesced stores
  __syncthreads();
#pragma unroll
  for (int i = 0; i < 4; ++i)
#pragma unroll
    for (int r = 0; r < 4; ++r) {
      int row = wm + i * 16 + q * 4 + r;
#pragma unroll
      for (int j = 0; j < 4; ++j)
        sh[row * 136 + wn + j * 16 + lm] = f2bf(acc[i][j][r]);
    }
  __syncthreads();
  int cc = tid & 15;
#pragma unroll
  for (int g = 0; g < 8; ++g) {
    int rr = (tid >> 4) + g * 16;
    v8s v = *(const v8s*)(sh + rr * 136 + cc * 8);
    *(v8s*)(xib + (size_t)(mb * 128 + rr) * DI + nb * 128 + cc * 8) = v;
  }
}

// ------- streaming causal depthwise conv + silu, 4-token strips + halo -------
__global__ __launch_bounds__(256) void k_conv(const short* __restrict__ xib,
                                              const float* __restrict__ conv_w,
                                              const float* __restrict__ conv_b,
                                              short* __restrict__ xcb,
                                              float* __restrict__ xclast) {
  int bid = blockIdx.x;            // 1024 = 8 b * 128 tc
  int b = bid >> 7, tc = bid & 127;
  int tid = threadIdx.x;
  int d8 = tid & 127, th = tid >> 7;
  int d = d8 * 8;
  int t0 = tc * 8 + th * 4;
  v4f cw[8];
  float cb[8];
#pragma unroll
  for (int i = 0; i < 8; ++i) {
    cw[i] = *(const v4f*)(conv_w + (d + i) * 4);
    cb[i] = conv_b[d + i];
  }
  float w0[8], w1[8], w2[8];
  const short* base = xib + (size_t)(b * L_) * DI + d;
  short* obase = xcb + (size_t)(b * L_) * DI + d;
#pragma unroll
  for (int i = 0; i < 8; ++i) { w0[i] = 0.f; w1[i] = 0.f; w2[i] = 0.f; }
  if (t0 >= 3) {
    v8s v0 = *(const v8s*)(base + (size_t)(t0 - 3) * DI);
    v8s v1 = *(const v8s*)(base + (size_t)(t0 - 2) * DI);
    v8s v2 = *(const v8s*)(base + (size_t)(t0 - 1) * DI);
#pragma unroll
    for (int i = 0; i < 8; ++i) { w0[i] = bf2f(v0[i]); w1[i] = bf2f(v1[i]); w2[i] = bf2f(v2[i]); }
  }
#pragma unroll
  for (int t = t0; t < t0 + 4; ++t) {
    v8s cur = *(const v8s*)(base + (size_t)t * DI);
    v8s ob;
#pragma unroll
    for (int i = 0; i < 8; ++i) {
      float xv = bf2f(cur[i]);
      float a = cb[i] + cw[i][0] * w0[i] + cw[i][1] * w1[i] + cw[i][2] * w2[i] + cw[i][3] * xv;
      float s = silu_fast(a);
      ob[i] = f2bf(s);
      if (t == L_ - 1) xclast[b * DI + d + i] = s;
      w0[i] = w1[i]; w1[i] = w2[i]; w2[i] = xv;
    }
    *(v8s*)(obase + (size_t)t * DI) = ob;
  }
}

// ------- fused: dbc split-K + Bmat + dt=softplus(...) + csum2 (4 waves) ------
__global__ __launch_bounds__(256) void k_dbcdt(const short* __restrict__ xcb,
                                               const short* __restrict__ wxb,
                                               const short* __restrict__ wdtb,
                                               const float* __restrict__ b_dt,
                                               float* __restrict__ Bmat,
                                               _Float16* __restrict__ dtO,
                                               float* __restrict__ csum2) {
  __shared__ float red[4 * 16 * 49];     // padded stride 49
  __shared__ short ta[16 * 32];          // dbc[:, :32] bf16, A-frag source
  int m = blockIdx.x;                    // mtile 0..511 (16 tokens)
  int tid = threadIdx.x, w = tid >> 6, l = tid & 63, lm = l & 15, q = l >> 4;
  v4f a0 = {0,0,0,0}, a1 = {0,0,0,0}, a2 = {0,0,0,0};
  const short* ap = xcb + (size_t)(m * 16 + lm) * DI + w * 256 + q * 8;
  const short* b0 = wxb + (size_t)lm * DI        + w * 256 + q * 8;
  const short* b1 = wxb + (size_t)(16 + lm) * DI + w * 256 + q * 8;
  const short* b2 = wxb + (size_t)(32 + lm) * DI + w * 256 + q * 8;
#pragma unroll
  for (int kk = 0; kk < 8; ++kk) {
    v8s a = *(const v8s*)(ap + kk * 32);
    a0 = __builtin_amdgcn_mfma_f32_16x16x32_bf16(a, *(const v8s*)(b0 + kk * 32), a0, 0, 0, 0);
    a1 = __builtin_amdgcn_mfma_f32_16x16x32_bf16(a, *(const v8s*)(b1 + kk * 32), a1, 0, 0, 0);
    a2 = __builtin_amdgcn_mfma_f32_16x16x32_bf16(a, *(const v8s*)(b2 + kk * 32), a2, 0, 0, 0);
  }
#pragma unroll
  for (int r = 0; r < 4; ++r) {
    int row = q * 4 + r;
    red[w * 784 + row * 49 + lm]      = a0[r];
    red[w * 784 + row * 49 + 16 + lm] = a1[r];
    red[w * 784 + row * 49 + 32 + lm] = a2[r];
  }
  __syncthreads();
  {
    int row = tid >> 4, c0 = tid & 15;
    int base = row * 49 + c0;
    float s0 = red[base] + red[784 + base] + red[1568 + base] + red[2352 + base];
    float s1 = red[base + 16] + red[784 + base + 16] + red[1568 + base + 16] + red[2352 + base + 16];
    float s2 = red[base + 32] + red[784 + base + 32] + red[1568 + base + 32] + red[2352 + base + 32];
    ta[row * 32 + c0]      = f2bf(s0);
    ta[row * 32 + 16 + c0] = f2bf(s1);
    Bmat[(size_t)(m * 16 + row) * DS + c0] = s2;
  }
  __syncthreads();
  // phase 2: dt = softplus(dbc32 @ W_dt.T + b_dt), wave w handles 16 col-tiles
  v8s ad = *(const v8s*)(ta + lm * 32 + q * 8);
#pragma unroll 4
  for (int nn = 0; nn < 16; ++nn) {
    int nt = w * 16 + nn;
    v8s bb = *(const v8s*)(wdtb + (size_t)(nt * 16 + lm) * DTR + q * 8);
    v4f zz = {0,0,0,0};
    v4f dd = __builtin_amdgcn_mfma_f32_16x16x32_bf16(ad, bb, zz, 0, 0, 0);
    int col = nt * 16 + lm;
    float bd = b_dt[col];
    float s = 0.f;
#pragma unroll
    for (int r = 0; r < 4; ++r) {
      float v = dd[r] + bd;
      float sp = (v > 15.f) ? v : __logf(1.f + __expf(v));
      dtO[(size_t)(m * 16 + q * 4 + r) * DI + col] = (_Float16)sp;
      s += sp;
    }
    s += __shfl_xor(s, 16, 64);
    s += __shfl_xor(s, 32, 64);
    if (q == 0) csum2[(size_t)m * DI + col] = s;
  }
}

// ------- suffix sums + C_last (merged small kernels) -------------------------
__global__ __launch_bounds__(256) void k_sufc(const float* __restrict__ csum2,
                                              const float* __restrict__ xclast,
                                              const float* __restrict__ w_x,
                                              float* __restrict__ SS,
                                              float* __restrict__ clast) {
  if (blockIdx.x < 32) {
    int b = blockIdx.x >> 2, dseg = blockIdx.x & 3;
    int d = dseg * 256 + threadIdx.x;
    float run = 0.f;
    for (int ch = 31; ch >= 0; --ch) {
      SS[(size_t)(b * 32 + ch) * DI + d] = run;
      run += csum2[(size_t)(b * 64 + 2 * ch + 1) * DI + d]
           + csum2[(size_t)(b * 64 + 2 * ch) * DI + d];
    }
  } else {
    int w2 = (int)(blockIdx.x - 32) * 4 + (threadIdx.x >> 6);  // 0..127
    int l = threadIdx.x & 63;
    int b = w2 >> 4, ss = w2 & 15;
    const v4f* xr = (const v4f*)(xclast + (size_t)b * DI);
    const v4f* wr = (const v4f*)(w_x + (size_t)(48 + ss) * DI);
    float s = 0.f;
#pragma unroll
    for (int i = 0; i < 4; ++i) {
      v4f a = xr[l + 64 * i], c = wr[l + 64 * i];
      s += a[0]*c[0] + a[1]*c[1] + a[2]*c[2] + a[3]*c[3];
    }
    s = wsum(s);
    if (l == 0) clast[b * 16 + ss] = s;
  }
}

// ---------------- scan collapsed to suffix-weighted reduction ----------------
__global__ __launch_bounds__(256) void k_scan(const _Float16* __restrict__ dt,
                                              const short* __restrict__ xcb,
                                              const float* __restrict__ Bmat,
                                              const float* __restrict__ SS,
                                              const float* __restrict__ Aneg,
                                              const float* __restrict__ clast,
                                              float* __restrict__ ypart) {
  __shared__ float lB[32 * 16];
  int bid = blockIdx.x;           // 8 b * 32 ch * 4 dg = 1024
  int b = bid >> 7, ch = (bid >> 2) & 31, dg = bid & 3;
  int tid = threadIdx.x;
  for (int i = tid; i < 32 * 16; i += 256)
    lB[i] = Bmat[(size_t)(b * L_ + ch * 32) * DS + i];
  __syncthreads();
  int d = dg * 256 + tid;
  float S = SS[(size_t)(b * 32 + ch) * DI + d];
  float As2[16];
#pragma unroll
  for (int s = 0; s < 16; ++s) As2[s] = Aneg[d * 16 + s] * 1.44269504f;
  float h[16];
#pragma unroll
  for (int s = 0; s < 16; ++s) h[s] = 0.f;
  const _Float16* dtp = dt + ((size_t)(b * L_ + ch * 32)) * DI + d;
  const short* xcp = xcb + ((size_t)(b * L_ + ch * 32)) * DI + d;
  for (int tl = 31; tl >= 0; --tl) {
    float dtv = (float)dtp[(size_t)tl * DI];
    float u   = bf2f(xcp[(size_t)tl * DI]);
    float c = dtv * u;
#pragma unroll
    for (int s = 0; s < 16; ++s)
      h[s] += __builtin_amdgcn_exp2f(As2[s] * S) * (c * lB[tl * 16 + s]);
    S += dtv;
  }
  float yp = 0.f;
#pragma unroll
  for (int s = 0; s < 16; ++s) yp += h[s] * clast[b * 16 + s];
  ypart[(size_t)(b * 32 + ch) * DI + d] = yp;
}

// ---------------- ylast = (sum ypart + D*xc_last) * silu(z_last) -------------
__global__ __launch_bounds__(256) void k_ylast(const float* __restrict__ ypart,
                                               const float* __restrict__ xclast,
                                               const float* __restrict__ Dp,
                                               const float* __restrict__ zlast,
                                               float* __restrict__ ylast) {
  int idx = blockIdx.x * 256 + threadIdx.x;  // 8192
  int b = idx >> 10, d = idx & 1023;
  float acc = 0.f;
#pragma unroll 8
  for (int ch = 0; ch < 32; ++ch) acc += ypart[(size_t)(b * 32 + ch) * DI + d];
  float y = acc + Dp[d] * xclast[idx];
  ylast[idx] = y * silu_fast(zlast[idx]);
}

// ---------------- out_last = y_last @ W_out.T (one output per wave) ----------
__global__ __launch_bounds__(256) void k_out(const float* __restrict__ ylast,
                                             const float* __restrict__ w_out,
                                             float* __restrict__ olast) {
  int w = blockIdx.x * 4 + (threadIdx.x >> 6);  // 4096
  int l = threadIdx.x & 63;
  int b = w >> 9, i = w & 511;
  const v4f* yr = (const v4f*)(ylast + (size_t)b * DI);
  const v4f* wr = (const v4f*)(w_out + (size_t)i * DI);
  float s = 0.f;
#pragma unroll
  for (int k = 0; k < 4; ++k) {
    v4f a = yr[l + 64 * k], c = wr[l + 64 * k];
    s += a[0]*c[0] + a[1]*c[1] + a[2]*c[2] + a[3]*c[3];
  }
  s = wsum(s);
  if (l == 0) olast[b * DM + i] = s;
}

// ---------------- layer norm over last token ---------------------------------
__global__ __launch_bounds__(256) void k_ln(const float* __restrict__ olast,
                                            const float* __restrict__ g,
                                            const float* __restrict__ be,
                                            float* __restrict__ lastn) {
  __shared__ float s1[256], s2[256];
  int b = blockIdx.x, tid = threadIdx.x;
  float v0 = olast[b * DM + tid], v1 = olast[b * DM + 256 + tid];
  s1[tid] = v0 + v1; s2[tid] = v0 * v0 + v1 * v1;
  __syncthreads();
  for (int o = 128; o > 0; o >>= 1) {
    if (tid < o) { s1[tid] += s1[tid + o]; s2[tid] += s2[tid + o]; }
    __syncthreads();
  }
  float mu = s1[0] / (float)DM;
  float var = s2[0] / (float)DM - mu * mu;
  float inv = 1.f / sqrtf(var + 1e-5f);
  lastn[b * DM + tid]       = (v0 - mu) * inv * g[tid]       + be[tid];
  lastn[b * DM + 256 + tid] = (v1 - mu) * inv * g[tid + 256] + be[tid + 256];
}

// ---------------- head GEMM (one output per wave) ----------------------------
__global__ __launch_bounds__(256) void k_head(const float* __restrict__ lastn,
                                              const float* __restrict__ hw,
                                              const float* __restrict__ hb,
                                              float* __restrict__ out) {
  int w = blockIdx.x * 4 + (threadIdx.x >> 6);  // 4096
  int l = threadIdx.x & 63;
  int b = w >> 9, o = w & 511;
  const v4f* xr = (const v4f*)(lastn + (size_t)b * DM);
  const v4f* wr = (const v4f*)(hw + (size_t)o * DM);
  float s = 0.f;
#pragma unroll
  for (int k = 0; k < 2; ++k) {
    v4f a = xr[l + 64 * k], c = wr[l + 64 * k];
    s += a[0]*c[0] + a[1]*c[1] + a[2]*c[2] + a[3]*c[3];
  }
  s = wsum(s);
  if (l == 0) out[b * DM + o] = s + hb[o];
}

extern "C" void kernel_launch(void* const* d_in, const int* in_sizes, int n_in,
                              void* d_out, int out_size, void* d_ws, size_t ws_size,
                              hipStream_t stream) {
  const float* x      = (const float*)d_in[0];
  const float* w_in   = (const float*)d_in[1];
  const float* conv_w = (const float*)d_in[2];
  const float* conv_b = (const float*)d_in[3];
  const float* w_x    = (const float*)d_in[4];
  const float* w_dt   = (const float*)d_in[5];
  const float* b_dt   = (const float*)d_in[6];
  const float* a_log  = (const float*)d_in[7];
  const float* Dp     = (const float*)d_in[8];
  const float* w_out  = (const float*)d_in[9];
  const float* ln_g   = (const float*)d_in[10];
  const float* ln_b   = (const float*)d_in[11];
  const float* head_W = (const float*)d_in[12];
  const float* head_b = (const float*)d_in[13];
  float* out = (float*)d_out;

  char* ws = (char*)d_ws;
  size_t off = 0;
  auto alloc = [&](size_t bytes) { void* p = ws + off; off += (bytes + 255) & ~(size_t)255; return p; };
  short* xb     = (short*)alloc((size_t)M_*DM*2);
  short* wib    = (short*)alloc((size_t)DI*DM*2);
  short* wxb    = (short*)alloc((size_t)48*DI*2);
  short* wdtb   = (short*)alloc((size_t)DI*DTR*2);
  float* Aneg   = (float*)alloc((size_t)DI*DS*4);
  short* xib    = (short*)alloc((size_t)M_*DI*2);
  short* xcb    = (short*)alloc((size_t)M_*DI*2);
  _Float16* dt  = (_Float16*)alloc((size_t)M_*DI*2);
  float* Bmat   = (float*)alloc((size_t)M_*DS*4);
  float* csum2  = (float*)alloc((size_t)512*DI*4);
  float* SS     = (float*)alloc((size_t)B_*32*DI*4);
  float* ypart  = (float*)alloc((size_t)B_*32*DI*4);
  float* zlast  = (float*)alloc((size_t)B_*DI*4);
  float* clast  = (float*)alloc((size_t)B_*DS*4);
  float* xclast = (float*)alloc((size_t)B_*DI*4);
  float* ylast  = (float*)alloc((size_t)B_*DI*4);
  float* olast  = (float*)alloc((size_t)B_*DM*4);
  float* lastn  = (float*)alloc((size_t)B_*DM*4);

  k_prep<<<6752, 256, 0, stream>>>(x, w_in, w_x, w_dt, a_log, xb, wib, wxb, wdtb, Aneg, zlast);
  k_gemm_xi<<<512, 256, 0, stream>>>(xb, wib, xib);
  k_conv<<<1024, 256, 0, stream>>>(xib, conv_w, conv_b, xcb, xclast);
  k_dbcdt<<<512, 256, 0, stream>>>(xcb, wxb, wdtb, b_dt, Bmat, dt, csum2);
  k_sufc<<<64, 256, 0, stream>>>(csum2, xclast, w_x, SS, clast);
  k_scan<<<1024, 256, 0, stream>>>(dt, xcb, Bmat, SS, Aneg, clast, ypart);
  k_ylast<<<32, 256, 0, stream>>>(ypart, xclast, Dp, zlast, ylast);
  k_out<<<1024, 256, 0, stream>>>(ylast, w_out, olast);
  k_ln<<<8, 256, 0, stream>>>(olast, ln_g, ln_b, lastn);
  k_head<<<1024, 256, 0, stream>>>(lastn, head_W, head_b, out);
}